// Round 9
// baseline (286.658 us; speedup 1.0000x reference)
//
#include <hip/hip_runtime.h>
#include <cstdint>
#include <cstddef>

typedef __bf16 bf16_t;
typedef __bf16 bf16x8 __attribute__((ext_vector_type(8)));
typedef __bf16 bf16x4 __attribute__((ext_vector_type(4)));
typedef _Float16 f16_t;
typedef _Float16 f16x4 __attribute__((ext_vector_type(4)));
typedef float f32x4 __attribute__((ext_vector_type(4)));

constexpr int BB = 2, SS = 2048, DD = 1024, HH = 16, HDIM = 64;
constexpr int BS = BB * SS;  // 4096
constexpr float LOG2E = 1.4426950408889634f;

// async global->LDS, 16B per lane; LDS dest is wave-uniform base + lane*16
__device__ __forceinline__ void glds16(const void* g, void* l) {
  __builtin_amdgcn_global_load_lds((const __attribute__((address_space(1))) void*)g,
                                   (__attribute__((address_space(3))) void*)l, 16, 0, 0);
}

#define MEMFENCE asm volatile("" ::: "memory")

// ---------------- fused input prep ----------------
// blocks [0,4096):      x fp32 -> bf16
// blocks [4096,5120):   wq/wk/wv/wo 64x64 tile transpose+convert
// blocks [5120,6144):   bias+mask -> f16 exp2-multiplier in attn-fragment order (vmq)
//   vmq chunk (uint4) index = (((b*16+qt)*32+kt)*16 + w*4 + j)*64 + lane
//   chunk j of (w,lane): qg=j>>1, mb in {2*(j&1), 2*(j&1)+1}; 8 f16 = [mb_lo r0..3][mb_hi r0..3]
//   value at q = qt*128 + w*32 + qg*16 + (lane&15), k = kt*64 + mb*16 + (lane>>4)*4 + r
__global__ __launch_bounds__(256) void prep_fused(
    const float* __restrict__ x, const float* __restrict__ wq, const float* __restrict__ wk,
    const float* __restrict__ wv, const float* __restrict__ wo, const float* __restrict__ bias,
    const int* __restrict__ mask, bf16_t* __restrict__ xb, bf16_t* __restrict__ wqkv_t,
    bf16_t* __restrict__ wo_t, f16_t* __restrict__ vmq) {
  __shared__ __align__(16) char smem[18432];
  float (*tile)[65] = (float(*)[65])smem;       // 64x65 f32 = 16640 B
  f16_t (*btile)[72] = (f16_t(*)[72])smem;      // 128x72 f16 = 18432 B
  int bid = blockIdx.x;
  int t = threadIdx.x;
  if (bid < 4096) {
    int i = bid * 256 + t;
    float4 v = ((const float4*)x)[i];
    union { bf16_t h[4]; uint2 u; } o;
    o.h[0] = (bf16_t)v.x; o.h[1] = (bf16_t)v.y; o.h[2] = (bf16_t)v.z; o.h[3] = (bf16_t)v.w;
    ((uint2*)xb)[i] = o.u;
  } else if (bid < 5120) {
    int id = bid - 4096;
    int which = id >> 8, tr = (id >> 4) & 15, tc = id & 15;
    const float* src = (which == 0) ? wq : (which == 1) ? wk : (which == 2) ? wv : wo;
    bf16_t* dst = (which < 3) ? wqkv_t : wo_t;
    int noff = (which < 3) ? which * 1024 : 0;
#pragma unroll
    for (int p = 0; p < 4; ++p) {
      int e = (p * 256 + t) * 4;
      int r = e >> 6, c = e & 63;
      float4 v = *(const float4*)&src[(size_t)(tr * 64 + r) * 1024 + tc * 64 + c];
      tile[r][c] = v.x; tile[r][c + 1] = v.y; tile[r][c + 2] = v.z; tile[r][c + 3] = v.w;
    }
    __syncthreads();
#pragma unroll
    for (int p = 0; p < 4; ++p) {
      int e = (p * 256 + t) * 4;
      int r = e >> 6, c = e & 63;
      union { bf16_t h[4]; uint2 u; } o;
#pragma unroll
      for (int j = 0; j < 4; ++j) o.h[j] = (bf16_t)tile[c + j][r];
      *(uint2*)&dst[(size_t)(noff + tc * 64 + r) * 1024 + tr * 64 + c] = o.u;
    }
  } else {
    int id = bid - 5120;  // [0,1024)
    int b = id >> 9, qt = (id >> 5) & 15, kt = id & 31;
    size_t base_in = ((size_t)(b * 2048 + qt * 128)) * 2048 + kt * 64;
#pragma unroll
    for (int p = 0; p < 4; ++p) {
      int c = p * 256 + t;          // [0,1024)
      int qr = c >> 3, k8 = (c & 7) * 8;
      const float* bp = &bias[base_in + (size_t)qr * 2048 + k8];
      const int* mp = &mask[base_in + (size_t)qr * 2048 + k8];
      float4 b0 = *(const float4*)bp;
      float4 b1 = *(const float4*)(bp + 4);
      int4 m0 = *(const int4*)mp;
      int4 m1 = *(const int4*)(mp + 4);
      union { f16_t h[8]; uint4 u; } o;
      o.h[0] = m0.x ? (f16_t)__builtin_amdgcn_exp2f(b0.x * LOG2E - 8.0f) : (f16_t)0.0f;
      o.h[1] = m0.y ? (f16_t)__builtin_amdgcn_exp2f(b0.y * LOG2E - 8.0f) : (f16_t)0.0f;
      o.h[2] = m0.z ? (f16_t)__builtin_amdgcn_exp2f(b0.z * LOG2E - 8.0f) : (f16_t)0.0f;
      o.h[3] = m0.w ? (f16_t)__builtin_amdgcn_exp2f(b0.w * LOG2E - 8.0f) : (f16_t)0.0f;
      o.h[4] = m1.x ? (f16_t)__builtin_amdgcn_exp2f(b1.x * LOG2E - 8.0f) : (f16_t)0.0f;
      o.h[5] = m1.y ? (f16_t)__builtin_amdgcn_exp2f(b1.y * LOG2E - 8.0f) : (f16_t)0.0f;
      o.h[6] = m1.z ? (f16_t)__builtin_amdgcn_exp2f(b1.z * LOG2E - 8.0f) : (f16_t)0.0f;
      o.h[7] = m1.w ? (f16_t)__builtin_amdgcn_exp2f(b1.w * LOG2E - 8.0f) : (f16_t)0.0f;
      *(uint4*)&btile[qr][k8] = o.u;
    }
    __syncthreads();
    int w = t >> 6, lane = t & 63, lo = lane & 15, quad = lane >> 4;
    size_t obase = ((size_t)(((b * 16 + qt) * 32 + kt) * 16)) * 64;  // uint4 units
#pragma unroll
    for (int j = 0; j < 4; ++j) {
      int row = w * 32 + (j >> 1) * 16 + lo;
      int mbl = 2 * (j & 1);
      union { f16_t h[8]; uint4 u; } o;
#pragma unroll
      for (int e = 0; e < 8; ++e)
        o.h[e] = btile[row][(mbl + (e >> 2)) * 16 + quad * 4 + (e & 3)];
      ((uint4*)vmq)[obase + (w * 4 + j) * 64 + lane] = o.u;
    }
  }
}

// ---------------- GEMM v2: pipelined k-loop (attn-v4 protocol) + XCD swizzle ----------------
// 3-buffer LDS ring, distance-2 prefetch, counted vmcnt(BATCH), setprio around MFMA.
// EPI: 0 = bf16 out, 1 = f32 + bias, 2 = QKV fused epilogue (q/k: LayerNorm -> qb/kb, v: raw -> Cb).
// Per k-step each thread issues exactly BATCH glds ops (4 for BNT=128, 3 for BNT=64).
template <int EPI, int BNT>
__global__ __launch_bounds__(256) void gemm_bt(
    const bf16_t* __restrict__ A, const bf16_t* __restrict__ Bt, bf16_t* __restrict__ Cb,
    float* __restrict__ Cf, const float* __restrict__ bias, int M, int N, int Kd,
    bf16_t* __restrict__ qb, bf16_t* __restrict__ kb, const float* __restrict__ bq,
    const float* __restrict__ bk, const float* __restrict__ q_scale,
    const float* __restrict__ k_scale) {
  constexpr int WNW = BNT / 2;   // wave n-strip width
  constexpr int NFR = WNW / 16;  // n frags per wave
  __shared__ __align__(16) bf16_t As[3][128][32];
  __shared__ __align__(16) bf16_t Bs[3][BNT][32];
  int tid = threadIdx.x;
  int lane = tid & 63, w = tid >> 6;
  int lo = lane & 15, quad = lane >> 4;
  int wm = w >> 1, wn = w & 1;
  // XCD-aware swizzle (grids are multiples of 8)
  int nbx = gridDim.x;
  int nwg = nbx * gridDim.y;
  int lid = blockIdx.y * nbx + blockIdx.x;
  int sid = (lid & 7) * (nwg >> 3) + (lid >> 3);
  int m0 = (sid / nbx) * 128, n0 = (sid % nbx) * BNT;
  int srow = lane >> 2;
  int scol = (lane & 3) * 8;
  const int NK = Kd >> 5;
  f32x4 acc[4][NFR] = {};

  auto stage = [&](int kk, int buf) {
    int r0 = (w * 2) * 16, r1 = (w * 2 + 1) * 16;
    glds16(&A[(size_t)(m0 + r0 + srow) * Kd + kk * 32 + scol], &As[buf][r0][0]);
    glds16(&A[(size_t)(m0 + r1 + srow) * Kd + kk * 32 + scol], &As[buf][r1][0]);
    if constexpr (BNT == 128) {
      glds16(&Bt[(size_t)(n0 + r0 + srow) * Kd + kk * 32 + scol], &Bs[buf][r0][0]);
      glds16(&Bt[(size_t)(n0 + r1 + srow) * Kd + kk * 32 + scol], &Bs[buf][r1][0]);
    } else {
      int rb = w * 16;
      glds16(&Bt[(size_t)(n0 + rb + srow) * Kd + kk * 32 + scol], &Bs[buf][rb][0]);
    }
  };

  stage(0, 0);
  MEMFENCE;
  stage(1, 1);
  int b0 = 0, b2 = 2;
#pragma unroll 1
  for (int kk = 0; kk < NK; ++kk) {
    if (kk == NK - 1) {
      asm volatile("s_waitcnt vmcnt(0)" ::: "memory");
    } else if constexpr (BNT == 128) {
      asm volatile("s_waitcnt vmcnt(4)" ::: "memory");
    } else {
      asm volatile("s_waitcnt vmcnt(3)" ::: "memory");
    }
    __builtin_amdgcn_s_barrier();
    MEMFENCE;
    if (kk + 2 < NK) stage(kk + 2, b2);
    __builtin_amdgcn_s_setprio(1);
    bf16x8 am[4], bn[NFR];
#pragma unroll
    for (int i = 0; i < 4; ++i)
      am[i] = *(const bf16x8*)&As[b0][wm * 64 + i * 16 + lo][quad * 8];
#pragma unroll
    for (int i = 0; i < NFR; ++i)
      bn[i] = *(const bf16x8*)&Bs[b0][wn * WNW + i * 16 + lo][quad * 8];
#pragma unroll
    for (int mi = 0; mi < 4; ++mi)
#pragma unroll
      for (int ni = 0; ni < NFR; ++ni)
        acc[mi][ni] = __builtin_amdgcn_mfma_f32_16x16x32_bf16(am[mi], bn[ni], acc[mi][ni], 0, 0, 0);
    __builtin_amdgcn_s_setprio(0);
    b0 = (b0 == 2) ? 0 : b0 + 1;
    b2 = (b2 == 2) ? 0 : b2 + 1;
  }

  bool plain = true;
  if constexpr (EPI == 2) {
    int which = n0 >> 10;  // 0=q, 1=k, 2=v
    if (which < 2) {
      plain = false;
      const float* badd = (which == 0) ? bq : bk;
      const float* sc = (which == 0) ? q_scale : k_scale;
      int hcol = (n0 + wn * WNW) & 1023;  // h*64
      int hh = hcol >> 6;
#pragma unroll
      for (int mi = 0; mi < 4; ++mi) {
#pragma unroll
        for (int r = 0; r < 4; ++r) {
          int row = m0 + wm * 64 + mi * 16 + quad * 4 + r;
          float xv[NFR];
          float sm = 0.0f;
#pragma unroll
          for (int ni = 0; ni < NFR; ++ni) {
            xv[ni] = acc[mi][ni][r] + badd[hcol + ni * 16 + lo];
            sm += xv[ni];
          }
#pragma unroll
          for (int off = 1; off <= 8; off <<= 1) sm += __shfl_xor(sm, off, 64);
          float mean = sm * (1.0f / 64.0f);
          float vs = 0.0f;
#pragma unroll
          for (int ni = 0; ni < NFR; ++ni) { xv[ni] -= mean; vs += xv[ni] * xv[ni]; }
#pragma unroll
          for (int off = 1; off <= 8; off <<= 1) vs += __shfl_xor(vs, off, 64);
          float rstd = rsqrtf(vs * (1.0f / 64.0f) + 1e-6f);
          if (which == 0) rstd *= 0.125f * LOG2E;  // 1/sqrt(HD)*log2(e): attn uses raw exp2
          int b = row >> 11, s = row & 2047;
          bf16_t* dst = ((which == 0) ? qb : kb) + (size_t)((b * 16 + hh) * 2048 + s) * 64;
#pragma unroll
          for (int ni = 0; ni < NFR; ++ni) {
            int e = ni * 16 + lo;
            // k pre-swizzled (16B chunk ^ (s&7)) for attn's linear glds; q linear
            int eo = (which == 0) ? e : ((((e >> 3) ^ (s & 7)) << 3) | (e & 7));
            dst[eo] = (bf16_t)(xv[ni] * rstd * sc[e]);
          }
        }
      }
    }
  }
  if (plain) {
#pragma unroll
    for (int mi = 0; mi < 4; ++mi) {
#pragma unroll
      for (int ni = 0; ni < NFR; ++ni) {
#pragma unroll
        for (int r = 0; r < 4; ++r) {
          int row = m0 + wm * 64 + mi * 16 + quad * 4 + r;
          int col = n0 + wn * WNW + ni * 16 + lo;
          float v = acc[mi][ni][r];
          if (EPI == 1)
            Cf[(size_t)row * N + col] = v + bias[col];
          else
            Cb[(size_t)row * N + col] = (bf16_t)v;
        }
      }
    }
  }
}

// ---------------- post-V: +bv, f16, transpose -> vt (pre-swizzled for attn glds) ----------------
__global__ __launch_bounds__(256) void postv(const bf16_t* __restrict__ Cqkv,
                                             const float* __restrict__ bv,
                                             f16_t* __restrict__ vt) {
  __shared__ float tile[64][65];
  int id2 = blockIdx.x;
  int t = threadIdx.x;
  int st = id2 & 31, h = (id2 >> 5) & 15, b = id2 >> 9;
#pragma unroll
  for (int p = 0; p < 2; ++p) {
    int e = (p * 256 + t) * 8;
    int r = e >> 6, c = e & 63;  // r = s-local, c = e-local
    bf16x8 v8 = *(const bf16x8*)&Cqkv[(size_t)(b * SS + st * 64 + r) * 3072 + 2048 + h * 64 + c];
#pragma unroll
    for (int j = 0; j < 8; ++j) tile[r][c + j] = (float)v8[j] + bv[h * 64 + c + j];
  }
  __syncthreads();
#pragma unroll
  for (int p = 0; p < 2; ++p) {
    int e = (p * 256 + t) * 8;
    int r = e >> 6, c = e & 63;  // r = e-row, c = s-col (multiple of 8)
    union { f16_t h[8]; uint4 u; } o;
#pragma unroll
    for (int j = 0; j < 8; ++j) o.h[j] = (f16_t)tile[c + j][r];
    *(uint4*)&vt[(size_t)((b * HH + h) * HDIM + r) * SS + st * 64 +
                 ((((c >> 3) ^ (r & 7)) << 3))] = o.u;
  }
}

// ---------------- flash attention v4b (unchanged from R8 best): QBLK=128, 4-buf ring, vmcnt(8) ----------------
#define ATTN_TILE(KT, CUR, STG, VMC)                                                          \
  {                                                                                           \
    if ((KT) == 31) { asm volatile("s_waitcnt vmcnt(0)" ::: "memory"); }                      \
    else            { asm volatile("s_waitcnt vmcnt(8)" ::: "memory"); }                      \
    __builtin_amdgcn_s_barrier();                                                             \
    if ((KT) + 2 < 32) {                                                                      \
      int k0n = ((KT) + 2) * 64;                                                              \
      _Pragma("unroll") for (int tt = 0; tt < 2; ++tt) {                                      \
        int i = w * 2 + tt;                                                                   \
        int r = i * 8 + (lane >> 3);                                                          \
        glds16(&kbase[(size_t)(k0n + r) * 64 + ((lane & 7) << 3)], (STG) + i * 1024);         \
        glds16(&vbase[(size_t)r * SS + k0n + ((lane & 7) << 3)], (STG) + 8192 + i * 1024);    \
      }                                                                                       \
    }                                                                                         \
    __builtin_amdgcn_s_setprio(1);                                                            \
    bf16x8 ka[4][2];                                                                          \
    _Pragma("unroll") for (int mb = 0; mb < 4; ++mb)                                          \
      _Pragma("unroll") for (int ec = 0; ec < 2; ++ec)                                        \
        ka[mb][ec] = *(const bf16x8*)((CUR) + (mb * 16 + lo) * 128 +                          \
                                      ((((ec << 2) | quad) ^ (lo & 7)) << 4));                \
    f16x4 pf[2][4];                                                                           \
    _Pragma("unroll") for (int qg = 0; qg < 2; ++qg)                                          \
      _Pragma("unroll") for (int mb = 0; mb < 4; ++mb) {                                      \
        f32x4 s = {};                                                                         \
        s = __builtin_amdgcn_mfma_f32_16x16x32_bf16(ka[mb][0], bqf[qg][0], s, 0, 0, 0);       \
        s = __builtin_amdgcn_mfma_f32_16x16x32_bf16(ka[mb][1], bqf[qg][1], s, 0, 0, 0);       \
        f16x4 p4;                                                                             \
        p4[0] = (f16_t)__builtin_amdgcn_exp2f(s[0]);                                          \
        p4[1] = (f16_t)__builtin_amdgcn_exp2f(s[1]);                                          \
        p4[2] = (f16_t)__builtin_amdgcn_exp2f(s[2]);                                          \
        p4[3] = (f16_t)__builtin_amdgcn_exp2f(s[3]);                                          \
        pf[qg][mb] = p4 * VMC[qg * 2 + (mb >> 1)].q[mb & 1];                                  \
      }                                                                                       \
    __builtin_amdgcn_s_setprio(0);                                                            \
    if ((KT) + 2 < 32) {  /* reload after last use of VMC: SSA renaming, no copies */         \
      _Pragma("unroll") for (int j = 0; j < 4; ++j)                                           \
        VMC[j].u = vmtile[(size_t)((KT) + 2) * 1024 + j * 64];                                \
    }                                                                                         \
    __builtin_amdgcn_s_setprio(1);                                                            \
    _Pragma("unroll") for (int mb = 0; mb < 4; ++mb) {                                        \
      _Pragma("unroll") for (int eb = 0; eb < 4; ++eb) {                                      \
        f16x4 va = *(const f16x4*)((CUR) + 8192 + (eb * 16 + lo) * 128 +                      \
                                   (((((mb << 1) | (quad >> 1)) ^ (lo & 7)) << 4) |           \
                                    ((quad & 1) << 3)));                                      \
        _Pragma("unroll") for (int qg = 0; qg < 2; ++qg)                                      \
          ot[qg][eb] =                                                                        \
              __builtin_amdgcn_mfma_f32_16x16x16f16(va, pf[qg][mb], ot[qg][eb], 0, 0, 0);     \
      }                                                                                       \
      _Pragma("unroll") for (int qg = 0; qg < 2; ++qg)                                        \
        lacc[qg] = __builtin_amdgcn_mfma_f32_16x16x16f16(ones, pf[qg][mb], lacc[qg], 0, 0, 0);\
    }                                                                                         \
    __builtin_amdgcn_s_setprio(0);                                                            \
  }

__global__ __launch_bounds__(256, 2) void attn_kernel(const bf16_t* __restrict__ qb,
                                                      const bf16_t* __restrict__ kb,
                                                      const f16_t* __restrict__ vt,
                                                      const f16_t* __restrict__ vmq,
                                                      bf16_t* __restrict__ xout) {
  __shared__ __align__(16) char lds[4][16384];  // 64KB ring: per buf K 8KB (64x128B swz) + V 8KB
  int tid = threadIdx.x;
  int lane = tid & 63, w = tid >> 6;
  int lo = lane & 15, quad = lane >> 4;
  // XCD swizzle (proven in R7/R8: FETCH 78->54MB): 64 consecutive sid per XCD = 4 whole heads
  int lid = blockIdx.x;
  int sid = ((lid & 7) << 6) | (lid >> 3);
  int qt = sid & 15, h = (sid >> 4) & 15, b = sid >> 8;
  size_t headoff = (size_t)(b * HH + h) * SS * HDIM;
  int q0 = qt * 128 + w * 32;
  const bf16_t* kbase = kb + headoff;
  const f16_t* vbase = vt + headoff;
  const uint4* vmtile =
      (const uint4*)vmq + ((size_t)((b * 16 + qt) * 32) * 16 + w * 4) * 64 + lane;

  bf16x8 bqf[2][2];
#pragma unroll
  for (int qg = 0; qg < 2; ++qg)
#pragma unroll
    for (int ec = 0; ec < 2; ++ec)
      bqf[qg][ec] =
          *(const bf16x8*)&qb[headoff + (size_t)(q0 + qg * 16 + lo) * HDIM + ec * 32 + quad * 8];

  f16x4 ones;
#pragma unroll
  for (int j = 0; j < 4; ++j) ones[j] = (f16_t)1.0f;

  f32x4 ot[2][4] = {};
  f32x4 lacc[2] = {};

  union VM { uint4 u; f16x4 q[2]; };
  VM vma[4], vmb[4];

  // prologue: [stage0:4g][vma:4v][stage1:4g][vmb:4v] -> 16 in flight; tile0's vmcnt(8)
  // retires stage0+vma exactly.
#pragma unroll
  for (int tt = 0; tt < 2; ++tt) {
    int i = w * 2 + tt;
    int r = i * 8 + (lane >> 3);
    glds16(&kbase[(size_t)r * 64 + ((lane & 7) << 3)], lds[0] + i * 1024);
    glds16(&vbase[(size_t)r * SS + ((lane & 7) << 3)], lds[0] + 8192 + i * 1024);
  }
  MEMFENCE;
#pragma unroll
  for (int j = 0; j < 4; ++j) vma[j].u = vmtile[j * 64];
  MEMFENCE;
#pragma unroll
  for (int tt = 0; tt < 2; ++tt) {
    int i = w * 2 + tt;
    int r = i * 8 + (lane >> 3);
    glds16(&kbase[(size_t)(64 + r) * 64 + ((lane & 7) << 3)], lds[1] + i * 1024);
    glds16(&vbase[(size_t)r * SS + 64 + ((lane & 7) << 3)], lds[1] + 8192 + i * 1024);
  }
  MEMFENCE;
#pragma unroll
  for (int j = 0; j < 4; ++j) vmb[j].u = vmtile[1024 + j * 64];

#pragma unroll 1
  for (int kt0 = 0; kt0 < 32; kt0 += 4) {
    ATTN_TILE(kt0 + 0, lds[0], lds[2], vma)
    ATTN_TILE(kt0 + 1, lds[1], lds[3], vmb)
    ATTN_TILE(kt0 + 2, lds[2], lds[0], vma)
    ATTN_TILE(kt0 + 3, lds[3], lds[1], vmb)
  }

#pragma unroll
  for (int qg = 0; qg < 2; ++qg) {
    float rl = 1.0f / lacc[qg][0];
    int q = q0 + qg * 16 + lo;
#pragma unroll
    for (int eb = 0; eb < 4; ++eb) {
      union { bf16_t h4[4]; uint2 u; } o;
#pragma unroll
      for (int r = 0; r < 4; ++r) o.h4[r] = (bf16_t)(ot[qg][eb][r] * rl);
      *(uint2*)&xout[(size_t)(b * SS + q) * DD + h * 64 + eb * 16 + quad * 4] = o.u;
    }
  }
}

extern "C" void kernel_launch(void* const* d_in, const int* in_sizes, int n_in, void* d_out,
                              int out_size, void* d_ws, size_t ws_size, hipStream_t stream) {
  const float* inputs_q = (const float*)d_in[0];
  const float* bias = (const float*)d_in[1];
  const int* mask = (const int*)d_in[2];
  const float* wq = (const float*)d_in[3];
  const float* bq = (const float*)d_in[4];
  const float* wk = (const float*)d_in[5];
  const float* bk = (const float*)d_in[6];
  const float* wv = (const float*)d_in[7];
  const float* bv = (const float*)d_in[8];
  const float* q_scale = (const float*)d_in[9];
  const float* k_scale = (const float*)d_in[10];
  const float* wo = (const float*)d_in[11];
  const float* bo = (const float*)d_in[12];
  float* out = (float*)d_out;

  // ws packing (67 MB; overlaps only between dead/live pairs):
  //   wo_t   0-2    (live to end)
  //   vmq    2-18   (live prep -> attn; f16 fragment-ordered exp2 bias factors)
  //   cqkv   19-43  (v cols only; live gemm_qkv -> postv)   xattn 19-27 (overlap; attn -> gemm_out)
  //   xb     43-51  (live prep -> gemm_qkv)      qb2  43-51 (overlap; live gemm_qkv -> attn)
  //   wqkv_t 51-57  (live prep -> gemm_qkv)      kb2  51-59 (overlap; live gemm_qkv -> attn)
  //   vtb    59-67  (live postv -> attn)
  // NOTE: qb2/kb2 overlap xb/wqkv_t which are gemm_qkv INPUTS — but gemm_qkv's fused epilogue
  // writes qb2/kb2 only AFTER its k-loop finished reading xb/wqkv_t for that block... NOT safe
  // across blocks (other blocks still reading). Move qb2/kb2 to dead bias/mask-free space:
  // use 27-35 (xattn ends at 27; cqkv v-region starts at 19+16=35? cqkv is [4096][3072]*2B=24MB
  // spanning 19-43, v cols interleaved). -> place qb2/kb2 at 67-83 (fresh, ws is 128MB-class).
  char* ws = (char*)d_ws;
  bf16_t* wo_t   = (bf16_t*)(ws);
  f16_t*  vmq    = (f16_t*)(ws + ((size_t)2 << 20));
  bf16_t* cqkv   = (bf16_t*)(ws + ((size_t)19 << 20));
  bf16_t* xattn  = (bf16_t*)(ws + ((size_t)19 << 20));
  bf16_t* xb     = (bf16_t*)(ws + ((size_t)43 << 20));
  bf16_t* wqkv_t = (bf16_t*)(ws + ((size_t)51 << 20));
  f16_t*  vtb    = (f16_t*)(ws + ((size_t)59 << 20));
  bf16_t* qb2    = (bf16_t*)(ws + ((size_t)67 << 20));
  bf16_t* kb2    = (bf16_t*)(ws + ((size_t)75 << 20));

  prep_fused<<<6144, 256, 0, stream>>>(inputs_q, wq, wk, wv, wo, bias, mask, xb, wqkv_t, wo_t, vmq);
  gemm_bt<2, 128><<<dim3(24, 32), 256, 0, stream>>>(xb, wqkv_t, cqkv, nullptr, nullptr, BS, 3072,
                                                    DD, qb2, kb2, bq, bk, q_scale, k_scale);
  postv<<<1024, 256, 0, stream>>>(cqkv, bv, vtb);
  attn_kernel<<<512, 256, 0, stream>>>(qb2, kb2, vtb, vmq, xattn);
  gemm_bt<1, 64><<<dim3(16, 32), 256, 0, stream>>>(xattn, wo_t, nullptr, out, bo, BS, 1024, DD,
                                                   nullptr, nullptr, nullptr, nullptr, nullptr,
                                                   nullptr);
}

// Round 10
// 285.424 us; speedup vs baseline: 1.0043x; 1.0043x over previous
//
#include <hip/hip_runtime.h>
#include <cstdint>
#include <cstddef>

typedef __bf16 bf16_t;
typedef __bf16 bf16x8 __attribute__((ext_vector_type(8)));
typedef __bf16 bf16x4 __attribute__((ext_vector_type(4)));
typedef _Float16 f16_t;
typedef _Float16 f16x4 __attribute__((ext_vector_type(4)));
typedef float f32x4 __attribute__((ext_vector_type(4)));

constexpr int BB = 2, SS = 2048, DD = 1024, HH = 16, HDIM = 64;
constexpr int BS = BB * SS;  // 4096
constexpr float LOG2E = 1.4426950408889634f;

// async global->LDS, 16B per lane; LDS dest is wave-uniform base + lane*16
__device__ __forceinline__ void glds16(const void* g, void* l) {
  __builtin_amdgcn_global_load_lds((const __attribute__((address_space(1))) void*)g,
                                   (__attribute__((address_space(3))) void*)l, 16, 0, 0);
}

// ---------------- fused input prep ----------------
// blocks [0,4096):      x fp32 -> bf16
// blocks [4096,5120):   wq/wk/wv/wo 64x64 tile transpose+convert
// blocks [5120,6144):   bias+mask -> f16 exp2-multiplier in attn-fragment order (vmq)
//   vmq chunk (uint4) index = (((b*16+qt)*32+kt)*16 + w*4 + j)*64 + lane
//   chunk j of (w,lane): qg=j>>1, mb in {2*(j&1), 2*(j&1)+1}; 8 f16 = [mb_lo r0..3][mb_hi r0..3]
//   value at q = qt*128 + w*32 + qg*16 + (lane&15), k = kt*64 + mb*16 + (lane>>4)*4 + r
__global__ __launch_bounds__(256) void prep_fused(
    const float* __restrict__ x, const float* __restrict__ wq, const float* __restrict__ wk,
    const float* __restrict__ wv, const float* __restrict__ wo, const float* __restrict__ bias,
    const int* __restrict__ mask, bf16_t* __restrict__ xb, bf16_t* __restrict__ wqkv_t,
    bf16_t* __restrict__ wo_t, f16_t* __restrict__ vmq) {
  __shared__ __align__(16) char smem[18432];
  float (*tile)[65] = (float(*)[65])smem;       // 64x65 f32 = 16640 B
  f16_t (*btile)[72] = (f16_t(*)[72])smem;      // 128x72 f16 = 18432 B
  int bid = blockIdx.x;
  int t = threadIdx.x;
  if (bid < 4096) {
    int i = bid * 256 + t;
    float4 v = ((const float4*)x)[i];
    union { bf16_t h[4]; uint2 u; } o;
    o.h[0] = (bf16_t)v.x; o.h[1] = (bf16_t)v.y; o.h[2] = (bf16_t)v.z; o.h[3] = (bf16_t)v.w;
    ((uint2*)xb)[i] = o.u;
  } else if (bid < 5120) {
    int id = bid - 4096;
    int which = id >> 8, tr = (id >> 4) & 15, tc = id & 15;
    const float* src = (which == 0) ? wq : (which == 1) ? wk : (which == 2) ? wv : wo;
    bf16_t* dst = (which < 3) ? wqkv_t : wo_t;
    int noff = (which < 3) ? which * 1024 : 0;
#pragma unroll
    for (int p = 0; p < 4; ++p) {
      int e = (p * 256 + t) * 4;
      int r = e >> 6, c = e & 63;
      float4 v = *(const float4*)&src[(size_t)(tr * 64 + r) * 1024 + tc * 64 + c];
      tile[r][c] = v.x; tile[r][c + 1] = v.y; tile[r][c + 2] = v.z; tile[r][c + 3] = v.w;
    }
    __syncthreads();
#pragma unroll
    for (int p = 0; p < 4; ++p) {
      int e = (p * 256 + t) * 4;
      int r = e >> 6, c = e & 63;
      union { bf16_t h[4]; uint2 u; } o;
#pragma unroll
      for (int j = 0; j < 4; ++j) o.h[j] = (bf16_t)tile[c + j][r];
      *(uint2*)&dst[(size_t)(noff + tc * 64 + r) * 1024 + tr * 64 + c] = o.u;
    }
  } else {
    int id = bid - 5120;  // [0,1024)
    int b = id >> 9, qt = (id >> 5) & 15, kt = id & 31;
    size_t base_in = ((size_t)(b * 2048 + qt * 128)) * 2048 + kt * 64;
#pragma unroll
    for (int p = 0; p < 4; ++p) {
      int c = p * 256 + t;          // [0,1024)
      int qr = c >> 3, k8 = (c & 7) * 8;
      const float* bp = &bias[base_in + (size_t)qr * 2048 + k8];
      const int* mp = &mask[base_in + (size_t)qr * 2048 + k8];
      float4 b0 = *(const float4*)bp;
      float4 b1 = *(const float4*)(bp + 4);
      int4 m0 = *(const int4*)mp;
      int4 m1 = *(const int4*)(mp + 4);
      union { f16_t h[8]; uint4 u; } o;
      o.h[0] = m0.x ? (f16_t)__builtin_amdgcn_exp2f(b0.x * LOG2E - 8.0f) : (f16_t)0.0f;
      o.h[1] = m0.y ? (f16_t)__builtin_amdgcn_exp2f(b0.y * LOG2E - 8.0f) : (f16_t)0.0f;
      o.h[2] = m0.z ? (f16_t)__builtin_amdgcn_exp2f(b0.z * LOG2E - 8.0f) : (f16_t)0.0f;
      o.h[3] = m0.w ? (f16_t)__builtin_amdgcn_exp2f(b0.w * LOG2E - 8.0f) : (f16_t)0.0f;
      o.h[4] = m1.x ? (f16_t)__builtin_amdgcn_exp2f(b1.x * LOG2E - 8.0f) : (f16_t)0.0f;
      o.h[5] = m1.y ? (f16_t)__builtin_amdgcn_exp2f(b1.y * LOG2E - 8.0f) : (f16_t)0.0f;
      o.h[6] = m1.z ? (f16_t)__builtin_amdgcn_exp2f(b1.z * LOG2E - 8.0f) : (f16_t)0.0f;
      o.h[7] = m1.w ? (f16_t)__builtin_amdgcn_exp2f(b1.w * LOG2E - 8.0f) : (f16_t)0.0f;
      *(uint4*)&btile[qr][k8] = o.u;
    }
    __syncthreads();
    int w = t >> 6, lane = t & 63, lo = lane & 15, quad = lane >> 4;
    size_t obase = ((size_t)(((b * 16 + qt) * 32 + kt) * 16)) * 64;  // uint4 units
#pragma unroll
    for (int j = 0; j < 4; ++j) {
      int row = w * 32 + (j >> 1) * 16 + lo;
      int mbl = 2 * (j & 1);
      union { f16_t h[8]; uint4 u; } o;
#pragma unroll
      for (int e = 0; e < 8; ++e)
        o.h[e] = btile[row][(mbl + (e >> 2)) * 16 + quad * 4 + (e & 3)];
      ((uint4*)vmq)[obase + (w * 4 + j) * 64 + lane] = o.u;
    }
  }
}

// ---------------- GEMM (R8's m97 structure + XCD swizzle) with optional fused epilogues ----------------
// k-loop is the MEASURED-BEST R8 structure: single-buffer LDS, vmcnt(0) drain, two barriers,
// no setprio (m190: setprio hurts lockstep GEMM; R9: ring+counted-vmcnt regressed 45->63us).
// EPI: 1 = f32 + bias (out-proj), 2 = QKV fused epilogue (q/k: LayerNorm -> qb/kb; v: bf16 -> Cb).
template <int EPI, int BNT>
__global__ __launch_bounds__(256) void gemm_bt(
    const bf16_t* __restrict__ A, const bf16_t* __restrict__ Bt, bf16_t* __restrict__ Cb,
    float* __restrict__ Cf, const float* __restrict__ bias, int M, int N, int Kd,
    bf16_t* __restrict__ qb, bf16_t* __restrict__ kb, const float* __restrict__ bq,
    const float* __restrict__ bk, const float* __restrict__ q_scale,
    const float* __restrict__ k_scale) {
  constexpr int WNW = BNT / 2;   // wave n-strip width
  constexpr int NFR = WNW / 16;  // n frags per wave
  __shared__ __align__(16) bf16_t As[128][32];
  __shared__ __align__(16) bf16_t Bs[BNT][32];
  int tid = threadIdx.x;
  int lane = tid & 63, w = tid >> 6;
  int lo = lane & 15, quad = lane >> 4;
  int wm = w >> 1, wn = w & 1;
  // XCD-aware swizzle (grids are multiples of 8): consecutive remapped ids share an XCD
  int nbx = gridDim.x;
  int nwg = nbx * gridDim.y;
  int lid = blockIdx.y * nbx + blockIdx.x;
  int sid = (lid & 7) * (nwg >> 3) + (lid >> 3);
  int m0 = (sid / nbx) * 128, n0 = (sid % nbx) * BNT;
  int srow = lane >> 2;
  int scol = (lane & 3) * 8;
  f32x4 acc[4][NFR] = {};
  for (int kk = 0; kk < Kd; kk += 32) {
#pragma unroll
    for (int t = 0; t < 2; ++t) {
      int rb = (w * 2 + t) * 16;
      glds16(&A[(size_t)(m0 + rb + srow) * Kd + kk + scol], &As[rb][0]);
      if (rb < BNT) glds16(&Bt[(size_t)(n0 + rb + srow) * Kd + kk + scol], &Bs[rb][0]);
    }
    asm volatile("s_waitcnt vmcnt(0)" ::: "memory");
    __syncthreads();
    bf16x8 am[4], bn[NFR];
#pragma unroll
    for (int i = 0; i < 4; ++i) am[i] = *(const bf16x8*)&As[wm * 64 + i * 16 + lo][quad * 8];
#pragma unroll
    for (int i = 0; i < NFR; ++i) bn[i] = *(const bf16x8*)&Bs[wn * WNW + i * 16 + lo][quad * 8];
#pragma unroll
    for (int mi = 0; mi < 4; ++mi)
#pragma unroll
      for (int ni = 0; ni < NFR; ++ni)
        acc[mi][ni] = __builtin_amdgcn_mfma_f32_16x16x32_bf16(am[mi], bn[ni], acc[mi][ni], 0, 0, 0);
    __syncthreads();
  }

  bool plain = true;
  if constexpr (EPI == 2) {
    int which = n0 >> 10;  // 0=q, 1=k, 2=v
    if (which < 2) {
      // fused LayerNorm epilogue on f32 accumulators: wave holds a full 64-elem head row
      // across lo-lanes x NFR frags (WNW=64=HDIM). shfl_xor(1,2,4,8) stays within quad group.
      plain = false;
      const float* badd = (which == 0) ? bq : bk;
      const float* sc = (which == 0) ? q_scale : k_scale;
      int hcol = (n0 + wn * WNW) & 1023;  // h*64
      int hh = hcol >> 6;
#pragma unroll
      for (int mi = 0; mi < 4; ++mi) {
#pragma unroll
        for (int r = 0; r < 4; ++r) {
          int row = m0 + wm * 64 + mi * 16 + quad * 4 + r;
          float xv[NFR];
          float sm = 0.0f;
#pragma unroll
          for (int ni = 0; ni < NFR; ++ni) {
            xv[ni] = acc[mi][ni][r] + badd[hcol + ni * 16 + lo];
            sm += xv[ni];
          }
#pragma unroll
          for (int off = 1; off <= 8; off <<= 1) sm += __shfl_xor(sm, off, 64);
          float mean = sm * (1.0f / 64.0f);
          float vs = 0.0f;
#pragma unroll
          for (int ni = 0; ni < NFR; ++ni) { xv[ni] -= mean; vs += xv[ni] * xv[ni]; }
#pragma unroll
          for (int off = 1; off <= 8; off <<= 1) vs += __shfl_xor(vs, off, 64);
          float rstd = rsqrtf(vs * (1.0f / 64.0f) + 1e-6f);
          if (which == 0) rstd *= 0.125f * LOG2E;  // 1/sqrt(HD)*log2(e): attn uses raw exp2
          int b = row >> 11, s = row & 2047;
          bf16_t* dst = ((which == 0) ? qb : kb) + (size_t)((b * 16 + hh) * 2048 + s) * 64;
#pragma unroll
          for (int ni = 0; ni < NFR; ++ni) {
            int e = ni * 16 + lo;
            // k pre-swizzled (16B chunk ^ (s&7)) for attn's linear glds; q linear
            int eo = (which == 0) ? e : ((((e >> 3) ^ (s & 7)) << 3) | (e & 7));
            dst[eo] = (bf16_t)(xv[ni] * rstd * sc[e]);
          }
        }
      }
    }
  }
  if (plain) {
#pragma unroll
    for (int mi = 0; mi < 4; ++mi) {
#pragma unroll
      for (int ni = 0; ni < NFR; ++ni) {
#pragma unroll
        for (int r = 0; r < 4; ++r) {
          int row = m0 + wm * 64 + mi * 16 + quad * 4 + r;
          int col = n0 + wn * WNW + ni * 16 + lo;
          float v = acc[mi][ni][r];
          if (EPI == 1)
            Cf[(size_t)row * N + col] = v + bias[col];
          else
            Cb[(size_t)row * N + col] = (bf16_t)v;
        }
      }
    }
  }
}

// ---------------- post-V: +bv, f16, transpose -> vt (pre-swizzled for attn glds) ----------------
__global__ __launch_bounds__(256) void postv(const bf16_t* __restrict__ Cqkv,
                                             const float* __restrict__ bv,
                                             f16_t* __restrict__ vt) {
  __shared__ float tile[64][65];
  int id2 = blockIdx.x;
  int t = threadIdx.x;
  int st = id2 & 31, h = (id2 >> 5) & 15, b = id2 >> 9;
#pragma unroll
  for (int p = 0; p < 2; ++p) {
    int e = (p * 256 + t) * 8;
    int r = e >> 6, c = e & 63;  // r = s-local, c = e-local
    bf16x8 v8 = *(const bf16x8*)&Cqkv[(size_t)(b * SS + st * 64 + r) * 3072 + 2048 + h * 64 + c];
#pragma unroll
    for (int j = 0; j < 8; ++j) tile[r][c + j] = (float)v8[j] + bv[h * 64 + c + j];
  }
  __syncthreads();
#pragma unroll
  for (int p = 0; p < 2; ++p) {
    int e = (p * 256 + t) * 8;
    int r = e >> 6, c = e & 63;  // r = e-row, c = s-col (multiple of 8)
    union { f16_t h[8]; uint4 u; } o;
#pragma unroll
    for (int j = 0; j < 8; ++j) o.h[j] = (f16_t)tile[c + j][r];
    *(uint4*)&vt[(size_t)((b * HH + h) * HDIM + r) * SS + st * 64 +
                 ((((c >> 3) ^ (r & 7)) << 3))] = o.u;
  }
}

// ---------------- flash attention v4b (byte-identical to R8 best, 59.1us): QBLK=128, 4-buf, vmcnt(8) ----------------
#define ATTN_TILE(KT, CUR, STG, VMC)                                                          \
  {                                                                                           \
    if ((KT) == 31) { asm volatile("s_waitcnt vmcnt(0)" ::: "memory"); }                      \
    else            { asm volatile("s_waitcnt vmcnt(8)" ::: "memory"); }                      \
    __builtin_amdgcn_s_barrier();                                                             \
    if ((KT) + 2 < 32) {                                                                      \
      int k0n = ((KT) + 2) * 64;                                                              \
      _Pragma("unroll") for (int tt = 0; tt < 2; ++tt) {                                      \
        int i = w * 2 + tt;                                                                   \
        int r = i * 8 + (lane >> 3);                                                          \
        glds16(&kbase[(size_t)(k0n + r) * 64 + ((lane & 7) << 3)], (STG) + i * 1024);         \
        glds16(&vbase[(size_t)r * SS + k0n + ((lane & 7) << 3)], (STG) + 8192 + i * 1024);    \
      }                                                                                       \
    }                                                                                         \
    __builtin_amdgcn_s_setprio(1);                                                            \
    bf16x8 ka[4][2];                                                                          \
    _Pragma("unroll") for (int mb = 0; mb < 4; ++mb)                                          \
      _Pragma("unroll") for (int ec = 0; ec < 2; ++ec)                                        \
        ka[mb][ec] = *(const bf16x8*)((CUR) + (mb * 16 + lo) * 128 +                          \
                                      ((((ec << 2) | quad) ^ (lo & 7)) << 4));                \
    f16x4 pf[2][4];                                                                           \
    _Pragma("unroll") for (int qg = 0; qg < 2; ++qg)                                          \
      _Pragma("unroll") for (int mb = 0; mb < 4; ++mb) {                                      \
        f32x4 s = {};                                                                         \
        s = __builtin_amdgcn_mfma_f32_16x16x32_bf16(ka[mb][0], bqf[qg][0], s, 0, 0, 0);       \
        s = __builtin_amdgcn_mfma_f32_16x16x32_bf16(ka[mb][1], bqf[qg][1], s, 0, 0, 0);       \
        f16x4 p4;                                                                             \
        p4[0] = (f16_t)__builtin_amdgcn_exp2f(s[0]);                                          \
        p4[1] = (f16_t)__builtin_amdgcn_exp2f(s[1]);                                          \
        p4[2] = (f16_t)__builtin_amdgcn_exp2f(s[2]);                                          \
        p4[3] = (f16_t)__builtin_amdgcn_exp2f(s[3]);                                          \
        pf[qg][mb] = p4 * VMC[qg * 2 + (mb >> 1)].q[mb & 1];                                  \
      }                                                                                       \
    __builtin_amdgcn_s_setprio(0);                                                            \
    if ((KT) + 2 < 32) {  /* reload after last use of VMC: SSA renaming, no copies */         \
      _Pragma("unroll") for (int j = 0; j < 4; ++j)                                           \
        VMC[j].u = vmtile[(size_t)((KT) + 2) * 1024 + j * 64];                                \
    }                                                                                         \
    __builtin_amdgcn_s_setprio(1);                                                            \
    _Pragma("unroll") for (int mb = 0; mb < 4; ++mb) {                                        \
      _Pragma("unroll") for (int eb = 0; eb < 4; ++eb) {                                      \
        f16x4 va = *(const f16x4*)((CUR) + 8192 + (eb * 16 + lo) * 128 +                      \
                                   (((((mb << 1) | (quad >> 1)) ^ (lo & 7)) << 4) |           \
                                    ((quad & 1) << 3)));                                      \
        _Pragma("unroll") for (int qg = 0; qg < 2; ++qg)                                      \
          ot[qg][eb] =                                                                        \
              __builtin_amdgcn_mfma_f32_16x16x16f16(va, pf[qg][mb], ot[qg][eb], 0, 0, 0);     \
      }                                                                                       \
      _Pragma("unroll") for (int qg = 0; qg < 2; ++qg)                                        \
        lacc[qg] = __builtin_amdgcn_mfma_f32_16x16x16f16(ones, pf[qg][mb], lacc[qg], 0, 0, 0);\
    }                                                                                         \
    __builtin_amdgcn_s_setprio(0);                                                            \
  }

__global__ __launch_bounds__(256, 2) void attn_kernel(const bf16_t* __restrict__ qb,
                                                      const bf16_t* __restrict__ kb,
                                                      const f16_t* __restrict__ vt,
                                                      const f16_t* __restrict__ vmq,
                                                      bf16_t* __restrict__ xout) {
  __shared__ __align__(16) char lds[4][16384];  // 64KB ring: per buf K 8KB (64x128B swz) + V 8KB
  int tid = threadIdx.x;
  int lane = tid & 63, w = tid >> 6;
  int lo = lane & 15, quad = lane >> 4;
  // XCD swizzle (proven in R7/R8: FETCH 78->54MB): 64 consecutive sid per XCD = 4 whole heads
  int lid = blockIdx.x;
  int sid = ((lid & 7) << 6) | (lid >> 3);
  int qt = sid & 15, h = (sid >> 4) & 15, b = sid >> 8;
  size_t headoff = (size_t)(b * HH + h) * SS * HDIM;
  int q0 = qt * 128 + w * 32;
  const bf16_t* kbase = kb + headoff;
  const f16_t* vbase = vt + headoff;
  const uint4* vmtile =
      (const uint4*)vmq + ((size_t)((b * 16 + qt) * 32) * 16 + w * 4) * 64 + lane;

  bf16x8 bqf[2][2];
#pragma unroll
  for (int qg = 0; qg < 2; ++qg)
#pragma unroll
    for (int ec = 0; ec < 2; ++ec)
      bqf[qg][ec] =
          *(const bf16x8*)&qb[headoff + (size_t)(q0 + qg * 16 + lo) * HDIM + ec * 32 + quad * 8];

  f16x4 ones;
#pragma unroll
  for (int j = 0; j < 4; ++j) ones[j] = (f16_t)1.0f;

  f32x4 ot[2][4] = {};
  f32x4 lacc[2] = {};

  union VM { uint4 u; f16x4 q[2]; };
  VM vma[4], vmb[4];

  // prologue: [stage0:4g][vma:4v][stage1:4g][vmb:4v] -> 16 in flight; tile0's vmcnt(8)
  // retires stage0+vma exactly.
#pragma unroll
  for (int tt = 0; tt < 2; ++tt) {
    int i = w * 2 + tt;
    int r = i * 8 + (lane >> 3);
    glds16(&kbase[(size_t)r * 64 + ((lane & 7) << 3)], lds[0] + i * 1024);
    glds16(&vbase[(size_t)r * SS + ((lane & 7) << 3)], lds[0] + 8192 + i * 1024);
  }
#pragma unroll
  for (int j = 0; j < 4; ++j) vma[j].u = vmtile[j * 64];
#pragma unroll
  for (int tt = 0; tt < 2; ++tt) {
    int i = w * 2 + tt;
    int r = i * 8 + (lane >> 3);
    glds16(&kbase[(size_t)(64 + r) * 64 + ((lane & 7) << 3)], lds[1] + i * 1024);
    glds16(&vbase[(size_t)r * SS + 64 + ((lane & 7) << 3)], lds[1] + 8192 + i * 1024);
  }
#pragma unroll
  for (int j = 0; j < 4; ++j) vmb[j].u = vmtile[1024 + j * 64];

#pragma unroll 1
  for (int kt0 = 0; kt0 < 32; kt0 += 4) {
    ATTN_TILE(kt0 + 0, lds[0], lds[2], vma)
    ATTN_TILE(kt0 + 1, lds[1], lds[3], vmb)
    ATTN_TILE(kt0 + 2, lds[2], lds[0], vma)
    ATTN_TILE(kt0 + 3, lds[3], lds[1], vmb)
  }

#pragma unroll
  for (int qg = 0; qg < 2; ++qg) {
    float rl = 1.0f / lacc[qg][0];
    int q = q0 + qg * 16 + lo;
#pragma unroll
    for (int eb = 0; eb < 4; ++eb) {
      union { bf16_t h4[4]; uint2 u; } o;
#pragma unroll
      for (int r = 0; r < 4; ++r) o.h4[r] = (bf16_t)(ot[qg][eb][r] * rl);
      *(uint2*)&xout[(size_t)(b * SS + q) * DD + h * 64 + eb * 16 + quad * 4] = o.u;
    }
  }
}

extern "C" void kernel_launch(void* const* d_in, const int* in_sizes, int n_in, void* d_out,
                              int out_size, void* d_ws, size_t ws_size, hipStream_t stream) {
  const float* inputs_q = (const float*)d_in[0];
  const float* bias = (const float*)d_in[1];
  const int* mask = (const int*)d_in[2];
  const float* wq = (const float*)d_in[3];
  const float* bq = (const float*)d_in[4];
  const float* wk = (const float*)d_in[5];
  const float* bk = (const float*)d_in[6];
  const float* wv = (const float*)d_in[7];
  const float* bv = (const float*)d_in[8];
  const float* q_scale = (const float*)d_in[9];
  const float* k_scale = (const float*)d_in[10];
  const float* wo = (const float*)d_in[11];
  const float* bo = (const float*)d_in[12];
  float* out = (float*)d_out;

  // ws packing:
  //   wo_t   0-2    (live to end)
  //   vmq    2-18   (live prep -> attn)
  //   cqkv   19-43  (v cols only; live gemm_qkv -> postv)   xattn 19-27 (overlap; attn -> gemm_out;
  //                  xattn overlaps only q-cols of cqkv, which are dead after gemm_qkv)
  //   xb     43-51  (live prep -> gemm_qkv)
  //   wqkv_t 51-57  (live prep -> gemm_qkv)
  //   vtb    59-67  (live postv -> attn)
  //   qb2    67-75  (live gemm_qkv epi -> attn)   kb2 75-83 (same) — fresh space, no overlap
  //                  with gemm inputs (validated in R9: passed with this layout)
  char* ws = (char*)d_ws;
  bf16_t* wo_t   = (bf16_t*)(ws);
  f16_t*  vmq    = (f16_t*)(ws + ((size_t)2 << 20));
  bf16_t* cqkv   = (bf16_t*)(ws + ((size_t)19 << 20));
  bf16_t* xattn  = (bf16_t*)(ws + ((size_t)19 << 20));
  bf16_t* xb     = (bf16_t*)(ws + ((size_t)43 << 20));
  bf16_t* wqkv_t = (bf16_t*)(ws + ((size_t)51 << 20));
  f16_t*  vtb    = (f16_t*)(ws + ((size_t)59 << 20));
  bf16_t* qb2    = (bf16_t*)(ws + ((size_t)67 << 20));
  bf16_t* kb2    = (bf16_t*)(ws + ((size_t)75 << 20));

  prep_fused<<<6144, 256, 0, stream>>>(inputs_q, wq, wk, wv, wo, bias, mask, xb, wqkv_t, wo_t, vmq);
  gemm_bt<2, 128><<<dim3(24, 32), 256, 0, stream>>>(xb, wqkv_t, cqkv, nullptr, nullptr, BS, 3072,
                                                    DD, qb2, kb2, bq, bk, q_scale, k_scale);
  postv<<<1024, 256, 0, stream>>>(cqkv, bv, vtb);
  attn_kernel<<<512, 256, 0, stream>>>(qb2, kb2, vtb, vmq, xattn);
  gemm_bt<1, 64><<<dim3(16, 32), 256, 0, stream>>>(xattn, wo_t, nullptr, out, bo, BS, 1024, DD,
                                                   nullptr, nullptr, nullptr, nullptr, nullptr,
                                                   nullptr);
}

// Round 11
// 268.199 us; speedup vs baseline: 1.0688x; 1.0642x over previous
//
#include <hip/hip_runtime.h>
#include <cstdint>
#include <cstddef>

typedef __bf16 bf16_t;
typedef __bf16 bf16x8 __attribute__((ext_vector_type(8)));
typedef __bf16 bf16x4 __attribute__((ext_vector_type(4)));
typedef _Float16 f16_t;
typedef _Float16 f16x4 __attribute__((ext_vector_type(4)));
typedef float f32x4 __attribute__((ext_vector_type(4)));

constexpr int BB = 2, SS = 2048, DD = 1024, HH = 16, HDIM = 64;
constexpr int BS = BB * SS;  // 4096
constexpr float LOG2E = 1.4426950408889634f;

// async global->LDS, 16B per lane; LDS dest is wave-uniform base + lane*16
__device__ __forceinline__ void glds16(const void* g, void* l) {
  __builtin_amdgcn_global_load_lds((const __attribute__((address_space(1))) void*)g,
                                   (__attribute__((address_space(3))) void*)l, 16, 0, 0);
}

// ---------------- fused input prep (byte-identical to R8) ----------------
// blocks [0,4096):      x fp32 -> bf16
// blocks [4096,5120):   wq/wk/wv/wo 64x64 tile transpose+convert
// blocks [5120,6144):   bias+mask -> f16 exp2-multiplier in attn-fragment order (vmq)
__global__ __launch_bounds__(256) void prep_fused(
    const float* __restrict__ x, const float* __restrict__ wq, const float* __restrict__ wk,
    const float* __restrict__ wv, const float* __restrict__ wo, const float* __restrict__ bias,
    const int* __restrict__ mask, bf16_t* __restrict__ xb, bf16_t* __restrict__ wqkv_t,
    bf16_t* __restrict__ wo_t, f16_t* __restrict__ vmq) {
  __shared__ __align__(16) char smem[18432];
  float (*tile)[65] = (float(*)[65])smem;       // 64x65 f32 = 16640 B
  f16_t (*btile)[72] = (f16_t(*)[72])smem;      // 128x72 f16 = 18432 B
  int bid = blockIdx.x;
  int t = threadIdx.x;
  if (bid < 4096) {
    int i = bid * 256 + t;
    float4 v = ((const float4*)x)[i];
    union { bf16_t h[4]; uint2 u; } o;
    o.h[0] = (bf16_t)v.x; o.h[1] = (bf16_t)v.y; o.h[2] = (bf16_t)v.z; o.h[3] = (bf16_t)v.w;
    ((uint2*)xb)[i] = o.u;
  } else if (bid < 5120) {
    int id = bid - 4096;
    int which = id >> 8, tr = (id >> 4) & 15, tc = id & 15;
    const float* src = (which == 0) ? wq : (which == 1) ? wk : (which == 2) ? wv : wo;
    bf16_t* dst = (which < 3) ? wqkv_t : wo_t;
    int noff = (which < 3) ? which * 1024 : 0;
#pragma unroll
    for (int p = 0; p < 4; ++p) {
      int e = (p * 256 + t) * 4;
      int r = e >> 6, c = e & 63;
      float4 v = *(const float4*)&src[(size_t)(tr * 64 + r) * 1024 + tc * 64 + c];
      tile[r][c] = v.x; tile[r][c + 1] = v.y; tile[r][c + 2] = v.z; tile[r][c + 3] = v.w;
    }
    __syncthreads();
#pragma unroll
    for (int p = 0; p < 4; ++p) {
      int e = (p * 256 + t) * 4;
      int r = e >> 6, c = e & 63;
      union { bf16_t h[4]; uint2 u; } o;
#pragma unroll
      for (int j = 0; j < 4; ++j) o.h[j] = (bf16_t)tile[c + j][r];
      *(uint2*)&dst[(size_t)(noff + tc * 64 + r) * 1024 + tr * 64 + c] = o.u;
    }
  } else {
    int id = bid - 5120;  // [0,1024)
    int b = id >> 9, qt = (id >> 5) & 15, kt = id & 31;
    size_t base_in = ((size_t)(b * 2048 + qt * 128)) * 2048 + kt * 64;
#pragma unroll
    for (int p = 0; p < 4; ++p) {
      int c = p * 256 + t;          // [0,1024)
      int qr = c >> 3, k8 = (c & 7) * 8;
      const float* bp = &bias[base_in + (size_t)qr * 2048 + k8];
      const int* mp = &mask[base_in + (size_t)qr * 2048 + k8];
      float4 b0 = *(const float4*)bp;
      float4 b1 = *(const float4*)(bp + 4);
      int4 m0 = *(const int4*)mp;
      int4 m1 = *(const int4*)(mp + 4);
      union { f16_t h[8]; uint4 u; } o;
      o.h[0] = m0.x ? (f16_t)__builtin_amdgcn_exp2f(b0.x * LOG2E - 8.0f) : (f16_t)0.0f;
      o.h[1] = m0.y ? (f16_t)__builtin_amdgcn_exp2f(b0.y * LOG2E - 8.0f) : (f16_t)0.0f;
      o.h[2] = m0.z ? (f16_t)__builtin_amdgcn_exp2f(b0.z * LOG2E - 8.0f) : (f16_t)0.0f;
      o.h[3] = m0.w ? (f16_t)__builtin_amdgcn_exp2f(b0.w * LOG2E - 8.0f) : (f16_t)0.0f;
      o.h[4] = m1.x ? (f16_t)__builtin_amdgcn_exp2f(b1.x * LOG2E - 8.0f) : (f16_t)0.0f;
      o.h[5] = m1.y ? (f16_t)__builtin_amdgcn_exp2f(b1.y * LOG2E - 8.0f) : (f16_t)0.0f;
      o.h[6] = m1.z ? (f16_t)__builtin_amdgcn_exp2f(b1.z * LOG2E - 8.0f) : (f16_t)0.0f;
      o.h[7] = m1.w ? (f16_t)__builtin_amdgcn_exp2f(b1.w * LOG2E - 8.0f) : (f16_t)0.0f;
      *(uint4*)&btile[qr][k8] = o.u;
    }
    __syncthreads();
    int w = t >> 6, lane = t & 63, lo = lane & 15, quad = lane >> 4;
    size_t obase = ((size_t)(((b * 16 + qt) * 32 + kt) * 16)) * 64;  // uint4 units
#pragma unroll
    for (int j = 0; j < 4; ++j) {
      int row = w * 32 + (j >> 1) * 16 + lo;
      int mbl = 2 * (j & 1);
      union { f16_t h[8]; uint4 u; } o;
#pragma unroll
      for (int e = 0; e < 8; ++e)
        o.h[e] = btile[row][(mbl + (e >> 2)) * 16 + quad * 4 + (e & 3)];
      ((uint4*)vmq)[obase + (w * 4 + j) * 64 + lane] = o.u;
    }
  }
}

// ---------------- GEMM (R8 m97 schedule, BK=64): C[M,N] = A[M,K] * Bt[N,K]^T ----------------
// Same 2-barrier vmcnt(0) schedule as R8 (R9/R10 proved pipelining it is neutral-to-negative),
// but K-step 32->64: halves the barrier-drain count, doubles MFMA per barrier (16->32).
// LDS rows are 128B -> 16-way bank conflict if linear; fixed with the attn-proven XOR swizzle:
// global source chunk is pre-swizzled per lane (glds16 global side IS per-lane), LDS dest linear,
// reads XOR the chunk back -> 2-way (free, m136). Coalescing unchanged (same 128B lines).
template <bool OUT_F32, int BNT>
__global__ __launch_bounds__(256) void gemm_bt(const bf16_t* __restrict__ A,
                                               const bf16_t* __restrict__ Bt,
                                               bf16_t* __restrict__ Cb, float* __restrict__ Cf,
                                               const float* __restrict__ bias, int M, int N,
                                               int Kd) {
  constexpr int WNW = BNT / 2;   // wave n-strip width
  constexpr int NFR = WNW / 16;  // n frags per wave
  __shared__ __align__(16) bf16_t As[128][64];
  __shared__ __align__(16) bf16_t Bs[BNT][64];
  int tid = threadIdx.x;
  int lane = tid & 63, w = tid >> 6;
  int lo = lane & 15, quad = lane >> 4;
  int wm = w >> 1, wn = w & 1;
  // XCD-aware swizzle (grids are multiples of 8): consecutive remapped ids share an XCD
  int nbx = gridDim.x;
  int nwg = nbx * gridDim.y;
  int lid = blockIdx.y * nbx + blockIdx.x;
  int sid = (lid & 7) * (nwg >> 3) + (lid >> 3);
  int m0 = (sid / nbx) * 128, n0 = (sid % nbx) * BNT;
  int srow = lane >> 3;                 // row within 8-row group
  int scol = ((lane & 7) ^ srow) * 8;   // pre-swizzled source chunk (8 elems = 16B)
  f32x4 acc[4][NFR] = {};
  for (int kk = 0; kk < Kd; kk += 64) {
#pragma unroll
    for (int i = 0; i < 4; ++i) {
      int rg = (i * 4 + w) * 8;  // wave-uniform 8-row group
      glds16(&A[(size_t)(m0 + rg + srow) * Kd + kk + scol], &As[rg][0]);
      if (rg < BNT) glds16(&Bt[(size_t)(n0 + rg + srow) * Kd + kk + scol], &Bs[rg][0]);
    }
    asm volatile("s_waitcnt vmcnt(0)" ::: "memory");
    __syncthreads();
    bf16x8 am[4][2], bn[NFR][2];
#pragma unroll
    for (int i = 0; i < 4; ++i)
#pragma unroll
      for (int s = 0; s < 2; ++s)
        am[i][s] = *(const bf16x8*)((const char*)&As[wm * 64 + i * 16 + lo][0] +
                                    ((((s << 2) | quad) ^ (lo & 7)) << 4));
#pragma unroll
    for (int i = 0; i < NFR; ++i)
#pragma unroll
      for (int s = 0; s < 2; ++s)
        bn[i][s] = *(const bf16x8*)((const char*)&Bs[wn * WNW + i * 16 + lo][0] +
                                    ((((s << 2) | quad) ^ (lo & 7)) << 4));
#pragma unroll
    for (int mi = 0; mi < 4; ++mi)
#pragma unroll
      for (int ni = 0; ni < NFR; ++ni) {
        acc[mi][ni] =
            __builtin_amdgcn_mfma_f32_16x16x32_bf16(am[mi][0], bn[ni][0], acc[mi][ni], 0, 0, 0);
        acc[mi][ni] =
            __builtin_amdgcn_mfma_f32_16x16x32_bf16(am[mi][1], bn[ni][1], acc[mi][ni], 0, 0, 0);
      }
    __syncthreads();
  }
#pragma unroll
  for (int mi = 0; mi < 4; ++mi) {
#pragma unroll
    for (int ni = 0; ni < NFR; ++ni) {
#pragma unroll
      for (int r = 0; r < 4; ++r) {
        int row = m0 + wm * 64 + mi * 16 + quad * 4 + r;
        int col = n0 + wn * WNW + ni * 16 + lo;
        float v = acc[mi][ni][r];
        if (OUT_F32)
          Cf[(size_t)row * N + col] = v + bias[col];
        else
          Cb[(size_t)row * N + col] = (bf16_t)v;
      }
    }
  }
}

// ---------------- fused post-QKV (byte-identical to R8): LN(q,k) vectorized | V transpose ----------------
__global__ __launch_bounds__(256) void postqkv(const bf16_t* __restrict__ Cqkv,
                                               const float* __restrict__ bq,
                                               const float* __restrict__ bk,
                                               const float* __restrict__ bv,
                                               const float* __restrict__ q_scale,
                                               const float* __restrict__ k_scale,
                                               bf16_t* __restrict__ qb, bf16_t* __restrict__ kb,
                                               f16_t* __restrict__ vt) {
  __shared__ float tile[64][65];
  int bid = blockIdx.x;
  int t = threadIdx.x;
  if (bid < 4096) {
    int vec2 = bid * 32 + ((t >> 6) << 3) + ((t & 63) >> 3);
    int mode = vec2 >> 16;
    int vec = vec2 & 65535;
    int bs = vec >> 4, h = vec & 15;
    int b = bs >> 11, s = bs & 2047;
    int e0 = (t & 7) * 8;
    const float* badd = (mode == 0) ? bq : bk;
    const float* sc = (mode == 0) ? q_scale : k_scale;
    bf16_t* dst = (mode == 0) ? qb : kb;
    bf16x8 v8 = *(const bf16x8*)&Cqkv[(size_t)bs * 3072 + mode * 1024 + h * 64 + e0];
    float xv[8];
    float sum = 0.0f;
#pragma unroll
    for (int j = 0; j < 8; ++j) { xv[j] = (float)v8[j] + badd[h * 64 + e0 + j]; sum += xv[j]; }
#pragma unroll
    for (int off = 1; off <= 4; off <<= 1) sum += __shfl_xor(sum, off, 64);
    float mean = sum * (1.0f / 64.0f);
    float vs = 0.0f;
#pragma unroll
    for (int j = 0; j < 8; ++j) { xv[j] -= mean; vs += xv[j] * xv[j]; }
#pragma unroll
    for (int off = 1; off <= 4; off <<= 1) vs += __shfl_xor(vs, off, 64);
    float rstd = rsqrtf(vs * (1.0f / 64.0f) + 1e-6f);
    if (mode == 0) rstd *= 0.125f * LOG2E;  // 1/sqrt(HD) * log2(e): attn uses raw exp2
    union { bf16_t h[8]; uint4 u; } o;
#pragma unroll
    for (int j = 0; j < 8; ++j) o.h[j] = (bf16_t)(xv[j] * rstd * sc[e0 + j]);
    // k: XOR-swizzle 16B chunks within the 128B row (q stays linear)
    int ch = (mode == 0) ? (t & 7) : ((t & 7) ^ (s & 7));
    *(uint4*)&dst[(size_t)((b * 16 + h) * 2048 + s) * 64 + ch * 8] = o.u;
  } else {
    int id2 = bid - 4096;
    int st = id2 & 31, h = (id2 >> 5) & 15, b = id2 >> 9;
#pragma unroll
    for (int p = 0; p < 2; ++p) {
      int e = (p * 256 + t) * 8;
      int r = e >> 6, c = e & 63;  // r = s-local, c = e-local
      bf16x8 v8 = *(const bf16x8*)&Cqkv[(size_t)(b * SS + st * 64 + r) * 3072 + 2048 + h * 64 + c];
#pragma unroll
      for (int j = 0; j < 8; ++j) tile[r][c + j] = (float)v8[j] + bv[h * 64 + c + j];
    }
    __syncthreads();
#pragma unroll
    for (int p = 0; p < 2; ++p) {
      int e = (p * 256 + t) * 8;
      int r = e >> 6, c = e & 63;  // r = e-row, c = s-col (multiple of 8)
      union { f16_t h[8]; uint4 u; } o;
#pragma unroll
      for (int j = 0; j < 8; ++j) o.h[j] = (f16_t)tile[c + j][r];
      *(uint4*)&vt[(size_t)((b * HH + h) * HDIM + r) * SS + st * 64 +
                   ((((c >> 3) ^ (r & 7)) << 3))] = o.u;
    }
  }
}

// ---------------- flash attention v4b (byte-identical to R8 best, 59.1us) ----------------
#define ATTN_TILE(KT, CUR, STG, VMC)                                                          \
  {                                                                                           \
    if ((KT) == 31) { asm volatile("s_waitcnt vmcnt(0)" ::: "memory"); }                      \
    else            { asm volatile("s_waitcnt vmcnt(8)" ::: "memory"); }                      \
    __builtin_amdgcn_s_barrier();                                                             \
    if ((KT) + 2 < 32) {                                                                      \
      int k0n = ((KT) + 2) * 64;                                                              \
      _Pragma("unroll") for (int tt = 0; tt < 2; ++tt) {                                      \
        int i = w * 2 + tt;                                                                   \
        int r = i * 8 + (lane >> 3);                                                          \
        glds16(&kbase[(size_t)(k0n + r) * 64 + ((lane & 7) << 3)], (STG) + i * 1024);         \
        glds16(&vbase[(size_t)r * SS + k0n + ((lane & 7) << 3)], (STG) + 8192 + i * 1024);    \
      }                                                                                       \
    }                                                                                         \
    __builtin_amdgcn_s_setprio(1);                                                            \
    bf16x8 ka[4][2];                                                                          \
    _Pragma("unroll") for (int mb = 0; mb < 4; ++mb)                                          \
      _Pragma("unroll") for (int ec = 0; ec < 2; ++ec)                                        \
        ka[mb][ec] = *(const bf16x8*)((CUR) + (mb * 16 + lo) * 128 +                          \
                                      ((((ec << 2) | quad) ^ (lo & 7)) << 4));                \
    f16x4 pf[2][4];                                                                           \
    _Pragma("unroll") for (int qg = 0; qg < 2; ++qg)                                          \
      _Pragma("unroll") for (int mb = 0; mb < 4; ++mb) {                                      \
        f32x4 s = {};                                                                         \
        s = __builtin_amdgcn_mfma_f32_16x16x32_bf16(ka[mb][0], bqf[qg][0], s, 0, 0, 0);       \
        s = __builtin_amdgcn_mfma_f32_16x16x32_bf16(ka[mb][1], bqf[qg][1], s, 0, 0, 0);       \
        f16x4 p4;                                                                             \
        p4[0] = (f16_t)__builtin_amdgcn_exp2f(s[0]);                                          \
        p4[1] = (f16_t)__builtin_amdgcn_exp2f(s[1]);                                          \
        p4[2] = (f16_t)__builtin_amdgcn_exp2f(s[2]);                                          \
        p4[3] = (f16_t)__builtin_amdgcn_exp2f(s[3]);                                          \
        pf[qg][mb] = p4 * VMC[qg * 2 + (mb >> 1)].q[mb & 1];                                  \
      }                                                                                       \
    __builtin_amdgcn_s_setprio(0);                                                            \
    if ((KT) + 2 < 32) {  /* reload after last use of VMC: SSA renaming, no copies */         \
      _Pragma("unroll") for (int j = 0; j < 4; ++j)                                           \
        VMC[j].u = vmtile[(size_t)((KT) + 2) * 1024 + j * 64];                                \
    }                                                                                         \
    __builtin_amdgcn_s_setprio(1);                                                            \
    _Pragma("unroll") for (int mb = 0; mb < 4; ++mb) {                                        \
      _Pragma("unroll") for (int eb = 0; eb < 4; ++eb) {                                      \
        f16x4 va = *(const f16x4*)((CUR) + 8192 + (eb * 16 + lo) * 128 +                      \
                                   (((((mb << 1) | (quad >> 1)) ^ (lo & 7)) << 4) |           \
                                    ((quad & 1) << 3)));                                      \
        _Pragma("unroll") for (int qg = 0; qg < 2; ++qg)                                      \
          ot[qg][eb] =                                                                        \
              __builtin_amdgcn_mfma_f32_16x16x16f16(va, pf[qg][mb], ot[qg][eb], 0, 0, 0);     \
      }                                                                                       \
      _Pragma("unroll") for (int qg = 0; qg < 2; ++qg)                                        \
        lacc[qg] = __builtin_amdgcn_mfma_f32_16x16x16f16(ones, pf[qg][mb], lacc[qg], 0, 0, 0);\
    }                                                                                         \
    __builtin_amdgcn_s_setprio(0);                                                            \
  }

__global__ __launch_bounds__(256, 2) void attn_kernel(const bf16_t* __restrict__ qb,
                                                      const bf16_t* __restrict__ kb,
                                                      const f16_t* __restrict__ vt,
                                                      const f16_t* __restrict__ vmq,
                                                      bf16_t* __restrict__ xout) {
  __shared__ __align__(16) char lds[4][16384];  // 64KB ring: per buf K 8KB (64x128B swz) + V 8KB
  int tid = threadIdx.x;
  int lane = tid & 63, w = tid >> 6;
  int lo = lane & 15, quad = lane >> 4;
  // XCD swizzle (proven in R7/R8: FETCH 78->54MB): 64 consecutive sid per XCD = 4 whole heads
  int lid = blockIdx.x;
  int sid = ((lid & 7) << 6) | (lid >> 3);
  int qt = sid & 15, h = (sid >> 4) & 15, b = sid >> 8;
  size_t headoff = (size_t)(b * HH + h) * SS * HDIM;
  int q0 = qt * 128 + w * 32;
  const bf16_t* kbase = kb + headoff;
  const f16_t* vbase = vt + headoff;
  const uint4* vmtile =
      (const uint4*)vmq + ((size_t)((b * 16 + qt) * 32) * 16 + w * 4) * 64 + lane;

  bf16x8 bqf[2][2];
#pragma unroll
  for (int qg = 0; qg < 2; ++qg)
#pragma unroll
    for (int ec = 0; ec < 2; ++ec)
      bqf[qg][ec] =
          *(const bf16x8*)&qb[headoff + (size_t)(q0 + qg * 16 + lo) * HDIM + ec * 32 + quad * 8];

  f16x4 ones;
#pragma unroll
  for (int j = 0; j < 4; ++j) ones[j] = (f16_t)1.0f;

  f32x4 ot[2][4] = {};
  f32x4 lacc[2] = {};

  union VM { uint4 u; f16x4 q[2]; };
  VM vma[4], vmb[4];

  // prologue: [stage0:4g][vma:4v][stage1:4g][vmb:4v] -> 16 in flight; tile0's vmcnt(8)
  // retires stage0+vma exactly.
#pragma unroll
  for (int tt = 0; tt < 2; ++tt) {
    int i = w * 2 + tt;
    int r = i * 8 + (lane >> 3);
    glds16(&kbase[(size_t)r * 64 + ((lane & 7) << 3)], lds[0] + i * 1024);
    glds16(&vbase[(size_t)r * SS + ((lane & 7) << 3)], lds[0] + 8192 + i * 1024);
  }
#pragma unroll
  for (int j = 0; j < 4; ++j) vma[j].u = vmtile[j * 64];
#pragma unroll
  for (int tt = 0; tt < 2; ++tt) {
    int i = w * 2 + tt;
    int r = i * 8 + (lane >> 3);
    glds16(&kbase[(size_t)(64 + r) * 64 + ((lane & 7) << 3)], lds[1] + i * 1024);
    glds16(&vbase[(size_t)r * SS + 64 + ((lane & 7) << 3)], lds[1] + 8192 + i * 1024);
  }
#pragma unroll
  for (int j = 0; j < 4; ++j) vmb[j].u = vmtile[1024 + j * 64];

#pragma unroll 1
  for (int kt0 = 0; kt0 < 32; kt0 += 4) {
    ATTN_TILE(kt0 + 0, lds[0], lds[2], vma)
    ATTN_TILE(kt0 + 1, lds[1], lds[3], vmb)
    ATTN_TILE(kt0 + 2, lds[2], lds[0], vma)
    ATTN_TILE(kt0 + 3, lds[3], lds[1], vmb)
  }

#pragma unroll
  for (int qg = 0; qg < 2; ++qg) {
    float rl = 1.0f / lacc[qg][0];
    int q = q0 + qg * 16 + lo;
#pragma unroll
    for (int eb = 0; eb < 4; ++eb) {
      union { bf16_t h4[4]; uint2 u; } o;
#pragma unroll
      for (int r = 0; r < 4; ++r) o.h4[r] = (bf16_t)(ot[qg][eb][r] * rl);
      *(uint2*)&xout[(size_t)(b * SS + q) * DD + h * 64 + eb * 16 + quad * 4] = o.u;
    }
  }
}

extern "C" void kernel_launch(void* const* d_in, const int* in_sizes, int n_in, void* d_out,
                              int out_size, void* d_ws, size_t ws_size, hipStream_t stream) {
  const float* inputs_q = (const float*)d_in[0];
  const float* bias = (const float*)d_in[1];
  const int* mask = (const int*)d_in[2];
  const float* wq = (const float*)d_in[3];
  const float* bq = (const float*)d_in[4];
  const float* wk = (const float*)d_in[5];
  const float* bk = (const float*)d_in[6];
  const float* wv = (const float*)d_in[7];
  const float* bv = (const float*)d_in[8];
  const float* q_scale = (const float*)d_in[9];
  const float* k_scale = (const float*)d_in[10];
  const float* wo = (const float*)d_in[11];
  const float* bo = (const float*)d_in[12];
  float* out = (float*)d_out;

  // ws packing (identical to R8):
  //   wo_t   0-2    (live to end)
  //   vmq    2-18   (live prep -> attn; f16 fragment-ordered exp2 bias factors)
  //   cqkv   19-43  (live gemm_qkv -> postqkv)   xattn 19-27 (overlap; live attn -> gemm_out)
  //   xb     43-51  (live prep -> gemm_qkv)      qb2  43-51 (overlap; live postqkv -> attn)
  //   wqkv_t 51-57  (live prep -> gemm_qkv)      kb2  51-59 (overlap; live postqkv -> attn)
  //   vtb    59-67  (live postqkv -> attn)
  char* ws = (char*)d_ws;
  bf16_t* wo_t   = (bf16_t*)(ws);
  f16_t*  vmq    = (f16_t*)(ws + ((size_t)2 << 20));
  bf16_t* cqkv   = (bf16_t*)(ws + ((size_t)19 << 20));
  bf16_t* xattn  = (bf16_t*)(ws + ((size_t)19 << 20));
  bf16_t* xb     = (bf16_t*)(ws + ((size_t)43 << 20));
  bf16_t* qb2    = (bf16_t*)(ws + ((size_t)43 << 20));
  bf16_t* wqkv_t = (bf16_t*)(ws + ((size_t)51 << 20));
  bf16_t* kb2    = (bf16_t*)(ws + ((size_t)51 << 20));
  f16_t*  vtb    = (f16_t*)(ws + ((size_t)59 << 20));

  prep_fused<<<6144, 256, 0, stream>>>(inputs_q, wq, wk, wv, wo, bias, mask, xb, wqkv_t, wo_t, vmq);
  gemm_bt<false, 128><<<dim3(24, 32), 256, 0, stream>>>(xb, wqkv_t, cqkv, nullptr, nullptr, BS,
                                                        3072, DD);
  postqkv<<<5120, 256, 0, stream>>>(cqkv, bq, bk, bv, q_scale, k_scale, qb2, kb2, vtb);
  attn_kernel<<<512, 256, 0, stream>>>(qb2, kb2, vtb, vmq, xattn);
  gemm_bt<true, 64><<<dim3(16, 32), 256, 0, stream>>>(xattn, wo_t, nullptr, out, bo, BS, 1024, DD);
}